// Round 5
// baseline (151.851 us; speedup 1.0000x reference)
//
#include <hip/hip_runtime.h>
#include <hip/hip_bf16.h>
#include <math.h>

#define NITEMS 100000
#define NUSERS 16384
#define GCN 128
#define GEO 32
#define HIDD 256
#define TD 128
#define RK 50

typedef unsigned int uint;
typedef unsigned short ushort;
typedef __bf16 bf16x8 __attribute__((ext_vector_type(8)));
typedef float f32x4 __attribute__((ext_vector_type(4)));

__device__ __forceinline__ ushort bfb(float x) {
  union { __hip_bfloat16 b; ushort u; } t; t.b = __float2bfloat16(x); return t.u;
}
__device__ __forceinline__ uint packbf2(float a, float b) {
  return (uint)bfb(a) | ((uint)bfb(b) << 16);
}
__device__ __forceinline__ float bflo(uint d) { return __uint_as_float(d << 16); }
__device__ __forceinline__ float bfhi(uint d) { return __uint_as_float(d & 0xffff0000u); }

union U4B { uint4 u; bf16x8 b; };
__device__ __forceinline__ bf16x8 ldfrag(const ushort* p) { U4B t; t.u = *(const uint4*)p; return t.b; }
__device__ __forceinline__ bf16x8 pack8(float4 a0, float4 a1) {
  U4B t;
  t.u.x = packbf2(a0.x, a0.y); t.u.y = packbf2(a0.z, a0.w);
  t.u.z = packbf2(a1.x, a1.y); t.u.w = packbf2(a1.z, a1.w);
  return t.b;
}

// ============ prep: weight bf16 convert (chunk-major [K/32][N][32]) + Wqk fold ============
__global__ __launch_bounds__(256) void prep_all(
    const float* __restrict__ Wi1, const float* __restrict__ Wi2,
    const float* __restrict__ Wu1, const float* __restrict__ Wu2,
    const float* __restrict__ Wq, const float* __restrict__ Wk,
    const float* __restrict__ bq,
    ushort* __restrict__ Wi1P, ushort* __restrict__ Wi2P,
    ushort* __restrict__ Wu1P, ushort* __restrict__ Wu2P,
    float* __restrict__ WqkS, float* __restrict__ bqk)
{
  int id = blockIdx.x * 256 + threadIdx.x;
  if (id < 40960) {                       // Wi1 [160][256]
    int k = id >> 8, c = id & 255;
    Wi1P[(k >> 5) * 8192 + c * 32 + (k & 31)] = bfb(Wi1[id]);
  } else if (id < 73728) {                // Wi2 [256][128]
    int i = id - 40960; int k = i >> 7, c = i & 127;
    Wi2P[(k >> 5) * 4096 + c * 32 + (k & 31)] = bfb(Wi2[i]);
  } else if (id < 139264) {               // Wu1 [256][256]
    int i = id - 73728; int k = i >> 8, c = i & 255;
    Wu1P[(k >> 5) * 8192 + c * 32 + (k & 31)] = bfb(Wu1[i]);
  } else if (id < 172032) {               // Wu2 [256][128]
    int i = id - 139264; int k = i >> 7, c = i & 127;
    Wu2P[(k >> 5) * 4096 + c * 32 + (k & 31)] = bfb(Wu2[i]);
  } else if (id < 188416) {               // WqkS[g][s] = Wq[g,:].Wk[s,:]
    int i = id - 172032; int g = i >> 7, s = i & 127;
    float acc = 0.f;
    for (int t = 0; t < 128; t += 4) {
      float4 a = *(const float4*)(Wq + g * 128 + t);
      float4 b = *(const float4*)(Wk + s * 128 + t);
      acc += a.x * b.x + a.y * b.y + a.z * b.z + a.w * b.w;
    }
    WqkS[g * 128 + s] = acc;
  } else if (id < 188544) {               // bqk[s] = bq.Wk[s,:]
    int s = id - 188416;
    float acc = 0.f;
    for (int t = 0; t < 128; t += 4) {
      float4 a = *(const float4*)(bq + t);
      float4 b = *(const float4*)(Wk + s * 128 + t);
      acc += a.x * b.x + a.y * b.y + a.z * b.z + a.w * b.w;
    }
    bqk[s] = acc;
  }
}

// ======================= fused MLP tower (MFMA bf16), item & user =======================
// 32 rows/block, 4 waves (each owns a 64/32-col slice of N). GEMM1 A-fragments
// load DIRECTLY from global per-lane (8 consecutive elems of one row) -> no
// staging phase, no pre-GEMM1 barriers. LDS holds only the hidden tile.
template <int ROWS, int K1, bool ITEM>
__global__ __launch_bounds__(256, 4) void mlp_kernel(
    const float* __restrict__ xmain,      // gcn_item / gcn_user
    const float* __restrict__ feat,       // item_feat / unused
    const float* __restrict__ Wg, const float* __restrict__ bg,
    const ushort* __restrict__ repB,      // unused for item
    const ushort* __restrict__ W1P, const float* __restrict__ b1,
    const ushort* __restrict__ W2P, const float* __restrict__ b2,
    float* __restrict__ outp, ushort* __restrict__ outb)
{
  constexpr int RF = ROWS / 16;          // 2
  constexpr int K1CH = K1 / 32;          // item 5, user 8
  __shared__ __align__(16) ushort s_h[ROWS * 264];   // hidden tile only
  __shared__ float s_red[ROWS * 4];
  __shared__ float s_inv[ROWS];

  const int tid = threadIdx.x;
  const int wid = tid >> 6, lane = tid & 63, g = lane >> 4, q = lane & 15;
  const int i0 = blockIdx.x * ROWS;      // grids divide exactly: no row guards

  // ---- GEMM1: [ROWS x K1] @ [K1 x 256], fully register-direct, barrier-free
  f32x4 acc[RF][4];
  #pragma unroll
  for (int cf = 0; cf < 4; ++cf) {
    float bv = b1[wid * 64 + cf * 16 + q];
    f32x4 t = {bv, bv, bv, bv};
    #pragma unroll
    for (int rf = 0; rf < RF; ++rf) acc[rf][cf] = t;
  }
  const ushort* bbase1 = W1P + (wid * 64 + q) * 32 + g * 8;

  #pragma unroll
  for (int kb = 0; kb < K1CH; ++kb) {
    bf16x8 af[RF], bfr[4];
    if (ITEM && kb == 0) {
      // geo chunk computed in-register: geo[c] = relu(f0*Wg[c] + f1*Wg[32+c] + bg[c])
      float4 w0a = *(const float4*)(Wg + g * 8),      w0b = *(const float4*)(Wg + g * 8 + 4);
      float4 w1a = *(const float4*)(Wg + 32 + g * 8), w1b = *(const float4*)(Wg + 32 + g * 8 + 4);
      float4 ba  = *(const float4*)(bg + g * 8),      bb = *(const float4*)(bg + g * 8 + 4);
      #pragma unroll
      for (int rf = 0; rf < RF; ++rf) {
        int row = i0 + q + 16 * rf;
        float2 f = *(const float2*)(feat + 2 * (size_t)row);
        float4 lo, hi;
        lo.x = fmaxf(fmaf(f.x, w0a.x, fmaf(f.y, w1a.x, ba.x)), 0.f);
        lo.y = fmaxf(fmaf(f.x, w0a.y, fmaf(f.y, w1a.y, ba.y)), 0.f);
        lo.z = fmaxf(fmaf(f.x, w0a.z, fmaf(f.y, w1a.z, ba.z)), 0.f);
        lo.w = fmaxf(fmaf(f.x, w0a.w, fmaf(f.y, w1a.w, ba.w)), 0.f);
        hi.x = fmaxf(fmaf(f.x, w0b.x, fmaf(f.y, w1b.x, bb.x)), 0.f);
        hi.y = fmaxf(fmaf(f.x, w0b.y, fmaf(f.y, w1b.y, bb.y)), 0.f);
        hi.z = fmaxf(fmaf(f.x, w0b.z, fmaf(f.y, w1b.z, bb.z)), 0.f);
        hi.w = fmaxf(fmaf(f.x, w0b.w, fmaf(f.y, w1b.w, bb.w)), 0.f);
        af[rf] = pack8(lo, hi);
      }
    } else if (!ITEM && kb >= K1CH - 4) {
      // user rep chunks: bf16 rows, direct 16B fragment load
      #pragma unroll
      for (int rf = 0; rf < RF; ++rf) {
        U4B t;
        t.u = *(const uint4*)(repB + (size_t)(i0 + q + 16 * rf) * TD + (kb - (K1CH - 4)) * 32 + g * 8);
        af[rf] = t.b;
      }
    } else {
      const int col = (ITEM ? (kb - 1) : kb) * 32 + g * 8;
      #pragma unroll
      for (int rf = 0; rf < RF; ++rf) {
        const float* rp = xmain + (size_t)(i0 + q + 16 * rf) * GCN + col;
        af[rf] = pack8(*(const float4*)rp, *(const float4*)(rp + 4));
      }
    }
    #pragma unroll
    for (int cf = 0; cf < 4; ++cf) bfr[cf] = ldfrag(bbase1 + kb * 8192 + cf * 512);
    #pragma unroll
    for (int rf = 0; rf < RF; ++rf)
      #pragma unroll
      for (int cf = 0; cf < 4; ++cf)
        acc[rf][cf] = __builtin_amdgcn_mfma_f32_16x16x32_bf16(af[rf], bfr[cf], acc[rf][cf], 0, 0, 0);
  }

  // ---- relu(hidden) -> LDS (stride 264)
  #pragma unroll
  for (int rf = 0; rf < RF; ++rf)
    #pragma unroll
    for (int cf = 0; cf < 4; ++cf)
      #pragma unroll
      for (int e = 0; e < 4; ++e)
        s_h[(16 * rf + 4 * g + e) * 264 + wid * 64 + cf * 16 + q] = bfb(fmaxf(acc[rf][cf][e], 0.f));
  __syncthreads();   // the ONLY barrier before GEMM2

  // ---- GEMM2: [ROWS x 256] @ [256 x 128]
  f32x4 acc2[RF][2];
  #pragma unroll
  for (int cf = 0; cf < 2; ++cf) {
    float bv = b2[wid * 32 + cf * 16 + q];
    f32x4 t = {bv, bv, bv, bv};
    #pragma unroll
    for (int rf = 0; rf < RF; ++rf) acc2[rf][cf] = t;
  }
  {
    const ushort* bbase2 = W2P + (wid * 32 + q) * 32 + g * 8;
    #pragma unroll
    for (int kb = 0; kb < 8; ++kb) {
      bf16x8 af[RF], bf2[2];
      #pragma unroll
      for (int rf = 0; rf < RF; ++rf) af[rf] = ldfrag(&s_h[(16 * rf + q) * 264 + kb * 32 + g * 8]);
      #pragma unroll
      for (int cf = 0; cf < 2; ++cf) bf2[cf] = ldfrag(bbase2 + kb * 4096 + cf * 512);
      #pragma unroll
      for (int rf = 0; rf < RF; ++rf)
        #pragma unroll
        for (int cf = 0; cf < 2; ++cf)
          acc2[rf][cf] = __builtin_amdgcn_mfma_f32_16x16x32_bf16(af[rf], bf2[cf], acc2[rf][cf], 0, 0, 0);
    }
  }

  // ---- row L2-norm
  #pragma unroll
  for (int rf = 0; rf < RF; ++rf) {
    #pragma unroll
    for (int e = 0; e < 4; ++e) {
      float p = acc2[rf][0][e] * acc2[rf][0][e] + acc2[rf][1][e] * acc2[rf][1][e];
      p += __shfl_xor(p, 1, 16); p += __shfl_xor(p, 2, 16);
      p += __shfl_xor(p, 4, 16); p += __shfl_xor(p, 8, 16);
      if (q == 0) s_red[(16 * rf + 4 * g + e) * 4 + wid] = p;
    }
  }
  __syncthreads();
  if (tid < ROWS) {
    float s = s_red[tid * 4] + s_red[tid * 4 + 1] + s_red[tid * 4 + 2] + s_red[tid * 4 + 3];
    s_inv[tid] = 1.f / fmaxf(sqrtf(s), 1e-12f);
  }
  __syncthreads();

  // ---- store f32 out (+ bf16 copy for the gather, item only)
  #pragma unroll
  for (int rf = 0; rf < RF; ++rf) {
    #pragma unroll
    for (int e = 0; e < 4; ++e) {
      int row = 16 * rf + 4 * g + e;
      int grow = i0 + row;
      float sc = s_inv[row];
      #pragma unroll
      for (int cf = 0; cf < 2; ++cf) {
        float v = acc2[rf][cf][e] * sc;
        outp[(size_t)grow * TD + wid * 32 + cf * 16 + q] = v;
        if constexpr (ITEM) outb[(size_t)grow * TD + wid * 32 + cf * 16 + q] = bfb(v);
      }
    }
  }
}

// ======================= qt = gue @ WqkS + bqk =======================
__global__ __launch_bounds__(256) void qt_kernel(
    const float* __restrict__ gcn_user, const float* __restrict__ WqkS,
    const float* __restrict__ bqk, float* __restrict__ qt)
{
  __shared__ float s_gue[16 * 132];
  const int tid = threadIdx.x;
  const int u0 = blockIdx.x * 16;
  #pragma unroll
  for (int r = 0; r < 8; ++r) {
    int lin = r * 256 + tid;
    int u = lin >> 7, c = lin & 127;
    s_gue[u * 132 + c] = gcn_user[(size_t)(u0 + u) * GCN + c];
  }
  __syncthreads();
  const int ul = tid >> 4, tx = tid & 15, c0 = tx * 8;
  float a[8];
  { float4 b4 = *(const float4*)(bqk + c0); float4 b5 = *(const float4*)(bqk + c0 + 4);
    a[0]=b4.x; a[1]=b4.y; a[2]=b4.z; a[3]=b4.w; a[4]=b5.x; a[5]=b5.y; a[6]=b5.z; a[7]=b5.w; }
  for (int g = 0; g < 128; ++g) {
    float x = s_gue[ul * 132 + g];
    float4 w4 = *(const float4*)(WqkS + g * 128 + c0);
    float4 w5 = *(const float4*)(WqkS + g * 128 + c0 + 4);
    a[0] = fmaf(x, w4.x, a[0]); a[1] = fmaf(x, w4.y, a[1]);
    a[2] = fmaf(x, w4.z, a[2]); a[3] = fmaf(x, w4.w, a[3]);
    a[4] = fmaf(x, w5.x, a[4]); a[5] = fmaf(x, w5.y, a[5]);
    a[6] = fmaf(x, w5.z, a[6]); a[7] = fmaf(x, w5.w, a[7]);
  }
  float* op = qt + (size_t)(u0 + ul) * TD + c0;
  *(float4*)op = make_float4(a[0], a[1], a[2], a[3]);
  *(float4*)(op + 4) = make_float4(a[4], a[5], a[6], a[7]);
}

// ======================= attention: one wave per user, single-pass =======================
__global__ __launch_bounds__(256) void attn_kernel(
    const int* __restrict__ user_items, const float* __restrict__ qt,
    const ushort* __restrict__ itemB, ushort* __restrict__ repB)
{
  __shared__ int s_idx[4][52];
  const int tid = threadIdx.x;
  const int wid = tid >> 6, lane = tid & 63, g = lane >> 4, q = lane & 15;
  const int u = blockIdx.x * 4 + wid;
  const int c0 = q * 8;

  if (lane < 52) s_idx[wid][lane] = (lane < 50) ? user_items[(size_t)u * RK + lane] : 0;
  float qv[8];
  { float4 a = *(const float4*)(qt + (size_t)u * TD + c0);
    float4 b = *(const float4*)(qt + (size_t)u * TD + c0 + 4);
    qv[0]=a.x; qv[1]=a.y; qv[2]=a.z; qv[3]=a.w; qv[4]=b.x; qv[5]=b.y; qv[6]=b.z; qv[7]=b.w; }
  // s_idx is wave-local: no block barrier needed

  uint4 h[13]; float sc[13];
  #pragma unroll
  for (int i = 0; i < 13; ++i) {
    int j = 4 * i + g;
    int idx = s_idx[wid][j];
    h[i] = *(const uint4*)(itemB + (size_t)idx * TD + c0);
    float p = bflo(h[i].x) * qv[0] + bfhi(h[i].x) * qv[1]
            + bflo(h[i].y) * qv[2] + bfhi(h[i].y) * qv[3]
            + bflo(h[i].z) * qv[4] + bfhi(h[i].z) * qv[5]
            + bflo(h[i].w) * qv[6] + bfhi(h[i].w) * qv[7];
    p += __shfl_xor(p, 1, 16); p += __shfl_xor(p, 2, 16);
    p += __shfl_xor(p, 4, 16); p += __shfl_xor(p, 8, 16);
    sc[i] = (j < RK) ? p : -3.0e38f;
  }
  float m = sc[0];
  #pragma unroll
  for (int i = 1; i < 13; ++i) m = fmaxf(m, sc[i]);
  m = fmaxf(m, __shfl_xor(m, 16, 64));
  m = fmaxf(m, __shfl_xor(m, 32, 64));
  float ssum = 0.f;
  #pragma unroll
  for (int i = 0; i < 13; ++i) { sc[i] = __expf(sc[i] - m); ssum += sc[i]; }
  ssum += __shfl_xor(ssum, 16, 64);
  ssum += __shfl_xor(ssum, 32, 64);
  const float inv = 1.f / ssum;
  float rep[8] = {0, 0, 0, 0, 0, 0, 0, 0};
  #pragma unroll
  for (int i = 0; i < 13; ++i) {
    float a = sc[i] * inv;
    rep[0] = fmaf(a, bflo(h[i].x), rep[0]); rep[1] = fmaf(a, bfhi(h[i].x), rep[1]);
    rep[2] = fmaf(a, bflo(h[i].y), rep[2]); rep[3] = fmaf(a, bfhi(h[i].y), rep[3]);
    rep[4] = fmaf(a, bflo(h[i].z), rep[4]); rep[5] = fmaf(a, bfhi(h[i].z), rep[5]);
    rep[6] = fmaf(a, bflo(h[i].w), rep[6]); rep[7] = fmaf(a, bfhi(h[i].w), rep[7]);
  }
  #pragma unroll
  for (int c = 0; c < 8; ++c) {
    rep[c] += __shfl_xor(rep[c], 16, 64);
    rep[c] += __shfl_xor(rep[c], 32, 64);
  }
  if (g == 0) {
    uint4 o;
    o.x = packbf2(rep[0], rep[1]); o.y = packbf2(rep[2], rep[3]);
    o.z = packbf2(rep[4], rep[5]); o.w = packbf2(rep[6], rep[7]);
    *(uint4*)(repB + (size_t)u * TD + c0) = o;
  }
}

extern "C" void kernel_launch(void* const* d_in, const int* in_sizes, int n_in,
                              void* d_out, int out_size, void* d_ws, size_t ws_size,
                              hipStream_t stream) {
  const float* item_feat  = (const float*)d_in[0];
  const float* gcn_item   = (const float*)d_in[1];
  const float* gcn_user   = (const float*)d_in[2];
  const int*   user_items = (const int*)  d_in[3];
  const float* Wg  = (const float*)d_in[4];
  const float* bg  = (const float*)d_in[5];
  const float* Wi1 = (const float*)d_in[6];
  const float* bi1 = (const float*)d_in[7];
  const float* Wi2 = (const float*)d_in[8];
  const float* bi2 = (const float*)d_in[9];
  const float* Wq  = (const float*)d_in[10];
  const float* bq  = (const float*)d_in[11];
  const float* Wk  = (const float*)d_in[12];
  // d_in[13] = bk: softmax-invariant, dropped
  const float* Wu1 = (const float*)d_in[14];
  const float* bu1 = (const float*)d_in[15];
  const float* Wu2 = (const float*)d_in[16];
  const float* bu2 = (const float*)d_in[17];
  float* out = (float*)d_out;

  // workspace layout (bytes): ~34.3 MB total
  char* ws = (char*)d_ws;
  ushort* Wi1P  = (ushort*)(ws + 0);         // 5*256*32*2  =  81920
  ushort* Wi2P  = (ushort*)(ws + 81920);     // 8*128*32*2  =  65536
  ushort* Wu1P  = (ushort*)(ws + 147456);    // 8*256*32*2  = 131072
  ushort* Wu2P  = (ushort*)(ws + 278528);    // 8*128*32*2  =  65536
  float*  WqkS  = (float*) (ws + 344064);    // 128*128*4   =  65536
  float*  bqk   = (float*) (ws + 409600);    // 128*4       =    512
  float*  qtb   = (float*) (ws + 410112);    // 16384*128*4 = 8388608
  ushort* itemB = (ushort*)(ws + 8798720);   // 100000*128*2 = 25600000
  ushort* repB  = (ushort*)(ws + 34398720);  // 16384*128*2 = 4194304

  prep_all<<<737, 256, 0, stream>>>(Wi1, Wi2, Wu1, Wu2, Wq, Wk, bq,
                                    Wi1P, Wi2P, Wu1P, Wu2P, WqkS, bqk);
  qt_kernel<<<NUSERS / 16, 256, 0, stream>>>(gcn_user, WqkS, bqk, qtb);
  mlp_kernel<32, 160, true><<<NITEMS / 32, 256, 0, stream>>>(
      gcn_item, item_feat, Wg, bg, nullptr, Wi1P, bi1, Wi2P, bi2, out, itemB);
  attn_kernel<<<NUSERS / 4, 256, 0, stream>>>(user_items, qtb, itemB, repB);
  mlp_kernel<32, 256, false><<<NUSERS / 32, 256, 0, stream>>>(
      gcn_user, nullptr, Wg, bg, repB, Wu1P, bu1, Wu2P, bu2, out + (size_t)NITEMS * TD, nullptr);
}